// Round 1
// baseline (538.430 us; speedup 1.0000x reference)
//
#include <hip/hip_runtime.h>
#include <hip/hip_fp16.h>

#define DIMF 1024
#define NHEADS 16
#define SEQ 2048
#define NPV 32
#define HD 64
#define LTOT 2080   // SEQ + NPV
#define LP 2112     // padded to 33*64
#define NB 4
#define BHN 64      // NB * NHEADS
#define NQT 33      // LP/64

typedef _Float16 f16x8 __attribute__((ext_vector_type(8)));
typedef float f32x4 __attribute__((ext_vector_type(4)));
typedef unsigned short u16x8 __attribute__((ext_vector_type(8)));

#if __has_builtin(__builtin_amdgcn_exp2f)
#define EXP2(x) __builtin_amdgcn_exp2f(x)
#else
#define EXP2(x) exp2f(x)
#endif

// ---------------- Kernel 1: paramvec add + LayerNorm + residual ----------------
// One block per (b, l) row. Writes residual (f32) to d_out, xn (f16) head-major.
__global__ __launch_bounds__(256) void prep_kernel(const float* __restrict__ x,
                                                   const float* __restrict__ pv,
                                                   float* __restrict__ out,
                                                   unsigned short* __restrict__ xnh) {
  int row = blockIdx.x;
  int b = row / LP, l = row - b * LP;
  int t = threadIdx.x;
  int h = t >> 4;               // d = 4t -> head = d>>6
  int dd = (t & 15) << 2;       // within-head offset
  unsigned short* dst = xnh + ((size_t)(b * NHEADS + h) * LP + l) * HD + dd;
  if (l >= LTOT) {              // zero pad rows (whole block uniform -> safe return)
    *reinterpret_cast<ushort4*>(dst) = make_ushort4(0, 0, 0, 0);
    return;
  }
  const float* xr = x + ((size_t)b * LTOT + l) * DIMF + t * 4;
  float4 v = *reinterpret_cast<const float4*>(xr);
  if (l >= SEQ) {
    float4 p = *reinterpret_cast<const float4*>(pv + (size_t)(l - SEQ) * DIMF + t * 4);
    v.x += p.x; v.y += p.y; v.z += p.z; v.w += p.w;
  }
  *reinterpret_cast<float4*>(out + ((size_t)b * LTOT + l) * DIMF + t * 4) = v;

  float s1 = v.x + v.y + v.z + v.w;
  float s2 = v.x * v.x + v.y * v.y + v.z * v.z + v.w * v.w;
#pragma unroll
  for (int o = 1; o < 64; o <<= 1) { s1 += __shfl_xor(s1, o); s2 += __shfl_xor(s2, o); }
  __shared__ float red[8];
  int wv = t >> 6;
  if ((t & 63) == 0) { red[wv] = s1; red[4 + wv] = s2; }
  __syncthreads();
  s1 = red[0] + red[1] + red[2] + red[3];
  s2 = red[4] + red[5] + red[6] + red[7];
  float mu = s1 * (1.0f / DIMF);
  float var = s2 * (1.0f / DIMF) - mu * mu;
  float rs = rsqrtf(var + 1e-5f);
  ushort4 o4;
  o4.x = __half_as_ushort(__float2half((v.x - mu) * rs));
  o4.y = __half_as_ushort(__float2half((v.y - mu) * rs));
  o4.z = __half_as_ushort(__float2half((v.z - mu) * rs));
  o4.w = __half_as_ushort(__float2half((v.w - mu) * rs));
  *reinterpret_cast<ushort4*>(dst) = o4;
}

// ---------------- Kernel 2: per-head transpose [BH][LP][64] -> [BH][64][LP] ----------------
__global__ __launch_bounds__(256) void transpose_kernel(const unsigned short* __restrict__ xnh,
                                                        unsigned short* __restrict__ xnt) {
  __shared__ unsigned short tile[64][72];
  int blk = blockIdx.x;
  int bh = blk / NQT, lt = blk - bh * NQT;
  int t = threadIdx.x;
  int rr = t >> 3;            // 0..31
  int c8 = (t & 7) << 3;      // 0..56
#pragma unroll
  for (int p = 0; p < 2; p++) {
    int ll = rr + p * 32;
    float4 v = *reinterpret_cast<const float4*>(xnh + ((size_t)bh * LP + lt * 64 + ll) * HD + c8);
    int cs = c8 ^ (((ll >> 3) & 7) << 3);   // XOR swizzle to break bank degeneracy
    *reinterpret_cast<float4*>(&tile[ll][cs]) = v;
  }
  __syncthreads();
  int l8 = (t & 7) << 3;
#pragma unroll
  for (int p = 0; p < 2; p++) {
    int d = rr + p * 32;
    u16x8 o;
#pragma unroll
    for (int j = 0; j < 8; j++) {
      o[j] = tile[l8 + j][d ^ ((t & 7) << 3)];   // (l8+j)>>3 == t&7
    }
    *reinterpret_cast<u16x8*>(xnt + ((size_t)bh * HD + d) * LP + lt * 64 + l8) = o;
  }
}

// ---------------- Kernel 3: flash attention, Q=K=V ----------------
// scores*0.125 via exp2(s*C - KSH); fixed shift 8 (diagonal guarantees lsum >= ~0.7).
static __device__ __forceinline__ f32x4 mfma16(f16x8 a, f16x8 b, f32x4 c) {
  return __builtin_amdgcn_mfma_f32_16x16x32_f16(a, b, c, 0, 0, 0);
}

#define CEXP 0.1803368801111f   // 0.125 * log2(e)
#define KSH  11.5415603271f     // 8 * log2(e)

template <int NK>
__device__ __forceinline__ void kv_step(int kv0,
                                        const unsigned short* __restrict__ Kb,
                                        const unsigned short* __restrict__ Vb,
                                        unsigned short (*plds)[72],
                                        f16x8 aq0, f16x8 aq1,
                                        f32x4 (&acc)[4], float (&lsum)[4],
                                        int lm, int lg) {
  f32x4 st[NK];
#pragma unroll
  for (int n = 0; n < NK; n++) {
    const unsigned short* kr = Kb + (size_t)(kv0 + n * 16 + lm) * HD + lg * 8;
    f16x8 bk0 = *reinterpret_cast<const f16x8*>(kr);
    f16x8 bk1 = *reinterpret_cast<const f16x8*>(kr + 32);
    f32x4 z = {0.f, 0.f, 0.f, 0.f};
    st[n] = mfma16(aq0, bk0, z);
    st[n] = mfma16(aq1, bk1, st[n]);
  }
#pragma unroll
  for (int n = 0; n < NK; n++) {
#pragma unroll
    for (int r = 0; r < 4; r++) {
      float p = EXP2(st[n][r] * CEXP - KSH);
      lsum[r] += p;
      plds[lg * 4 + r][n * 16 + lm] = __half_as_ushort(__float2half(p));
    }
  }
#pragma unroll
  for (int s = 0; s < NK / 2; s++) {
    f16x8 ap = *reinterpret_cast<const f16x8*>(&plds[lm][s * 32 + lg * 8]);
#pragma unroll
    for (int dn = 0; dn < 4; dn++) {
      const unsigned short* vr = Vb + (size_t)(dn * 16 + lm) * LP + kv0 + s * 32 + lg * 8;
      f16x8 bv = *reinterpret_cast<const f16x8*>(vr);
      acc[dn] = mfma16(ap, bv, acc[dn]);
    }
  }
}

__global__ __launch_bounds__(256) void attn_kernel(const unsigned short* __restrict__ xnh,
                                                   const unsigned short* __restrict__ xnt,
                                                   float* __restrict__ out) {
  __shared__ unsigned short plds_all[4][16][72];
  int bid = blockIdx.x;
  const int nwg = BHN * NQT;       // 2112, divisible by 8 -> bijective XCD swizzle
  const int cpx = nwg >> 3;
  int wg = (bid & 7) * cpx + (bid >> 3);
  int bh = wg / NQT, qt = wg - bh * NQT;
  int b = bh >> 4, h = bh & 15;
  int wid = threadIdx.x >> 6;
  int lane = threadIdx.x & 63;
  int q0 = qt * 64 + wid * 16;
  if (q0 >= LTOT) return;          // no barriers in this kernel -> safe
  int lm = lane & 15, lg = lane >> 4;
  unsigned short (*plds)[72] = plds_all[wid];
  const unsigned short* Kb = xnh + (size_t)bh * (LP * HD);
  const unsigned short* Vb = xnt + (size_t)bh * (HD * LP);

  // Q fragments hoisted (A-layout: row=lm, k=lg*8+i)
  f16x8 aq0 = *reinterpret_cast<const f16x8*>(Kb + (size_t)(q0 + lm) * HD + lg * 8);
  f16x8 aq1 = *reinterpret_cast<const f16x8*>(Kb + (size_t)(q0 + lm) * HD + 32 + lg * 8);

  f32x4 acc[4] = {{0.f,0.f,0.f,0.f},{0.f,0.f,0.f,0.f},{0.f,0.f,0.f,0.f},{0.f,0.f,0.f,0.f}};
  float lsum[4] = {0.f, 0.f, 0.f, 0.f};

  for (int kt = 0; kt < 32; ++kt)
    kv_step<4>(kt * 64, Kb, Vb, plds, aq0, aq1, acc, lsum, lm, lg);
  kv_step<2>(2048, Kb, Vb, plds, aq0, aq1, acc, lsum, lm, lg);  // last 32 kv

  // reduce row sums over the 16-lane column group
#pragma unroll
  for (int r = 0; r < 4; r++) {
    float s = lsum[r];
    s += __shfl_xor(s, 1); s += __shfl_xor(s, 2);
    s += __shfl_xor(s, 4); s += __shfl_xor(s, 8);
    lsum[r] = 1.0f / s;
  }
  // out[b][q0 + lg*4 + r][h*64 + dn*16 + lm] += acc/lsum  (residual already there)
  float* orow = out + ((size_t)b * LTOT + q0) * DIMF + h * HD;
#pragma unroll
  for (int r = 0; r < 4; r++) {
#pragma unroll
    for (int dn = 0; dn < 4; dn++) {
      float* p = orow + (size_t)(lg * 4 + r) * DIMF + dn * 16 + lm;
      *p = *p + acc[dn][r] * lsum[r];
    }
  }
}

extern "C" void kernel_launch(void* const* d_in, const int* in_sizes, int n_in,
                              void* d_out, int out_size, void* d_ws, size_t ws_size,
                              hipStream_t stream) {
  const float* x  = (const float*)d_in[0];
  const float* pv = (const float*)d_in[1];
  float* out = (float*)d_out;
  unsigned short* xnh = (unsigned short*)d_ws;                 // [BH][LP][64] f16, 17.3 MB
  unsigned short* xnt = xnh + (size_t)BHN * LP * HD;           // [BH][64][LP] f16, 17.3 MB
  prep_kernel<<<NB * LP, 256, 0, stream>>>(x, pv, out, xnh);
  transpose_kernel<<<BHN * NQT, 256, 0, stream>>>(xnh, xnt);
  attn_kernel<<<BHN * NQT, 256, 0, stream>>>(xnh, xnt, out);
}

// Round 2
// 168.962 us; speedup vs baseline: 3.1867x; 3.1867x over previous
//
#include <hip/hip_runtime.h>
#include <hip/hip_fp16.h>

#define DIMF 1024
#define NHEADS 16
#define SEQ 2048
#define NPV 32
#define HD 64
#define LTOT 2080   // SEQ + NPV
#define LP 2112     // padded to 33*64
#define NB 4
#define BHN 64      // NB * NHEADS
#define NQT 33      // LP/64

typedef _Float16 f16x8 __attribute__((ext_vector_type(8)));
typedef float f32x4 __attribute__((ext_vector_type(4)));
typedef unsigned short u16x8 __attribute__((ext_vector_type(8)));

#if __has_builtin(__builtin_amdgcn_exp2f)
#define EXP2(x) __builtin_amdgcn_exp2f(x)
#else
#define EXP2(x) exp2f(x)
#endif

// ---------------- Kernel 1: paramvec add + LayerNorm + residual ----------------
__global__ __launch_bounds__(256) void prep_kernel(const float* __restrict__ x,
                                                   const float* __restrict__ pv,
                                                   float* __restrict__ out,
                                                   unsigned short* __restrict__ xnh) {
  int row = blockIdx.x;
  int b = row / LP, l = row - b * LP;
  int t = threadIdx.x;
  int h = t >> 4;
  int dd = (t & 15) << 2;
  unsigned short* dst = xnh + ((size_t)(b * NHEADS + h) * LP + l) * HD + dd;
  if (l >= LTOT) {              // zero pad rows (block-uniform -> safe return)
    *reinterpret_cast<ushort4*>(dst) = make_ushort4(0, 0, 0, 0);
    return;
  }
  const float* xr = x + ((size_t)b * LTOT + l) * DIMF + t * 4;
  float4 v = *reinterpret_cast<const float4*>(xr);
  if (l >= SEQ) {
    float4 p = *reinterpret_cast<const float4*>(pv + (size_t)(l - SEQ) * DIMF + t * 4);
    v.x += p.x; v.y += p.y; v.z += p.z; v.w += p.w;
  }
  *reinterpret_cast<float4*>(out + ((size_t)b * LTOT + l) * DIMF + t * 4) = v;

  float s1 = v.x + v.y + v.z + v.w;
  float s2 = v.x * v.x + v.y * v.y + v.z * v.z + v.w * v.w;
#pragma unroll
  for (int o = 1; o < 64; o <<= 1) { s1 += __shfl_xor(s1, o); s2 += __shfl_xor(s2, o); }
  __shared__ float red[8];
  int wv = t >> 6;
  if ((t & 63) == 0) { red[wv] = s1; red[4 + wv] = s2; }
  __syncthreads();
  s1 = red[0] + red[1] + red[2] + red[3];
  s2 = red[4] + red[5] + red[6] + red[7];
  float mu = s1 * (1.0f / DIMF);
  float var = s2 * (1.0f / DIMF) - mu * mu;
  float rs = rsqrtf(var + 1e-5f);
  ushort4 o4;
  o4.x = __half_as_ushort(__float2half((v.x - mu) * rs));
  o4.y = __half_as_ushort(__float2half((v.y - mu) * rs));
  o4.z = __half_as_ushort(__float2half((v.z - mu) * rs));
  o4.w = __half_as_ushort(__float2half((v.w - mu) * rs));
  *reinterpret_cast<ushort4*>(dst) = o4;
}

// ---------------- Kernel 2: per-head transpose [BH][LP][64] -> [BH][64][LP] ----------------
__global__ __launch_bounds__(256) void transpose_kernel(const unsigned short* __restrict__ xnh,
                                                        unsigned short* __restrict__ xnt) {
  __shared__ unsigned short tile[64][72];
  int blk = blockIdx.x;
  int bh = blk / NQT, lt = blk - bh * NQT;
  int t = threadIdx.x;
  int rr = t >> 3;
  int c8 = (t & 7) << 3;
#pragma unroll
  for (int p = 0; p < 2; p++) {
    int ll = rr + p * 32;
    float4 v = *reinterpret_cast<const float4*>(xnh + ((size_t)bh * LP + lt * 64 + ll) * HD + c8);
    int cs = c8 ^ (((ll >> 3) & 7) << 3);
    *reinterpret_cast<float4*>(&tile[ll][cs]) = v;
  }
  __syncthreads();
  int l8 = (t & 7) << 3;
#pragma unroll
  for (int p = 0; p < 2; p++) {
    int d = rr + p * 32;
    u16x8 o;
#pragma unroll
    for (int j = 0; j < 8; j++) {
      o[j] = tile[l8 + j][d ^ ((t & 7) << 3)];
    }
    *reinterpret_cast<u16x8*>(xnt + ((size_t)bh * HD + d) * LP + lt * 64 + l8) = o;
  }
}

// ---------------- Kernel 3: flash attention, Q=K=V, LDS-staged + 2-phase pipeline ----------------
static __device__ __forceinline__ f32x4 mfma16(f16x8 a, f16x8 b, f32x4 c) {
  return __builtin_amdgcn_mfma_f32_16x16x32_f16(a, b, c, 0, 0, 0);
}

#define CEXP 0.1803368801111f   // 0.125 * log2(e)
#define KSH  11.5415603271f     // 8 * log2(e)

// Stage a 64x64 f16 tile into LDS (linear dest) with inverse-XOR-swizzled global
// source so that the swizzled read (group g at row r reads g^(r&7)) is conflict-free.
// g: base of tile in global (element 0 = row 0, col 0); stride in halves per row.
static __device__ __forceinline__ void stage_tile(const unsigned short* __restrict__ g,
                                                  int stride, unsigned short* lds,
                                                  int wid, int lane) {
#pragma unroll
  for (int c = 0; c < 2; c++) {
    int ci = (c * 4 + wid) * 64 + lane;          // 16B-chunk index 0..511
    int row = ci >> 3;                            // 8 chunks per 128B row
    int gcol = ((ci & 7) ^ (row & 7)) << 3;       // inverse swizzle on SOURCE
    const unsigned short* src = g + (size_t)row * stride + gcol;
    unsigned short* dst = lds + (size_t)(c * 4 + wid) * 512;   // wave-uniform base
    __builtin_amdgcn_global_load_lds(
        (const __attribute__((address_space(1))) unsigned int*)src,
        (__attribute__((address_space(3))) unsigned int*)dst, 16, 0, 0);
  }
}

template <int NK>
__device__ __forceinline__ void kv_step(const unsigned short* kt, const unsigned short* vt,
                                        unsigned short (*plds)[80],
                                        f16x8 aq0, f16x8 aq1,
                                        f32x4 (&acc)[4], float (&lsum)[4],
                                        int lm, int lg) {
  f32x4 st[NK];
#pragma unroll
  for (int n = 0; n < NK; n++) {
    int rr = n * 16 + lm;
    f16x8 bk0 = *reinterpret_cast<const f16x8*>(kt + rr * 64 + ((lg ^ (rr & 7)) << 3));
    f16x8 bk1 = *reinterpret_cast<const f16x8*>(kt + rr * 64 + (((lg + 4) ^ (rr & 7)) << 3));
    f32x4 z = {0.f, 0.f, 0.f, 0.f};
    st[n] = mfma16(aq0, bk0, z);
    st[n] = mfma16(aq1, bk1, st[n]);
  }
#pragma unroll
  for (int n = 0; n < NK; n++) {
#pragma unroll
    for (int r = 0; r < 4; r++) {
      float p = EXP2(st[n][r] * CEXP - KSH);
      lsum[r] += p;
      plds[lg * 4 + r][n * 16 + lm] = __half_as_ushort(__float2half(p));
    }
  }
#pragma unroll
  for (int s = 0; s < NK / 2; s++) {
    f16x8 ap = *reinterpret_cast<const f16x8*>(&plds[lm][s * 32 + lg * 8]);
#pragma unroll
    for (int dn = 0; dn < 4; dn++) {
      int rv = dn * 16 + lm;
      f16x8 bv = *reinterpret_cast<const f16x8*>(
          vt + rv * 64 + ((((s << 2) + lg) ^ (rv & 7)) << 3));
      acc[dn] = mfma16(ap, bv, acc[dn]);
    }
  }
}

__global__ __launch_bounds__(256) void attn_kernel(const unsigned short* __restrict__ xnh,
                                                   const unsigned short* __restrict__ xnt,
                                                   float* __restrict__ out) {
  __shared__ unsigned short ktile[2][64 * 64];
  __shared__ unsigned short vtile[2][64 * 64];
  __shared__ unsigned short plds_all[4][16][80];
  int bid = blockIdx.x;
  const int nwg = BHN * NQT;       // 2112, divisible by 8 -> bijective XCD swizzle
  const int cpx = nwg >> 3;
  int wg = (bid & 7) * cpx + (bid >> 3);
  int bh = wg / NQT, qt = wg - bh * NQT;
  int b = bh >> 4, h = bh & 15;
  int wid = threadIdx.x >> 6;
  int lane = threadIdx.x & 63;
  int q0 = qt * 64 + wid * 16;     // may exceed LTOT (pad rows, zeros) - store is guarded
  int lm = lane & 15, lg = lane >> 4;
  unsigned short (*plds)[80] = plds_all[wid];
  const unsigned short* Kb = xnh + (size_t)bh * (LP * HD);
  const unsigned short* Vb = xnt + (size_t)bh * (HD * LP);

  // Q fragments hoisted (A-layout: row=lm, k=lg*8+i)
  f16x8 aq0 = *reinterpret_cast<const f16x8*>(Kb + (size_t)(q0 + lm) * HD + lg * 8);
  f16x8 aq1 = *reinterpret_cast<const f16x8*>(Kb + (size_t)(q0 + lm) * HD + 32 + lg * 8);

  f32x4 acc[4] = {{0.f,0.f,0.f,0.f},{0.f,0.f,0.f,0.f},{0.f,0.f,0.f,0.f},{0.f,0.f,0.f,0.f}};
  float lsum[4] = {0.f, 0.f, 0.f, 0.f};

  // prologue: stage tile 0
  stage_tile(Kb, HD, &ktile[0][0], wid, lane);
  stage_tile(Vb, LP, &vtile[0][0], wid, lane);
  __syncthreads();   // drains vmcnt(0)

  int cur = 0;
  for (int t = 0; t < 32; ++t) {
    // issue next tile's stage BEFORE compute (latency hides under compute)
    int kv0n = (t + 1) * 64;
    stage_tile(Kb + (size_t)kv0n * HD, HD, &ktile[cur ^ 1][0], wid, lane);
    stage_tile(Vb + kv0n, LP, &vtile[cur ^ 1][0], wid, lane);
    kv_step<4>(&ktile[cur][0], &vtile[cur][0], plds, aq0, aq1, acc, lsum, lm, lg);
    __syncthreads();   // vmcnt(0) drain + barrier: next buffer ready
    cur ^= 1;
  }
  kv_step<2>(&ktile[cur][0], &vtile[cur][0], plds, aq0, aq1, acc, lsum, lm, lg);  // kv 2048..2079

  // reduce row sums over the 16-lane column group
#pragma unroll
  for (int r = 0; r < 4; r++) {
    float s = lsum[r];
    s += __shfl_xor(s, 1); s += __shfl_xor(s, 2);
    s += __shfl_xor(s, 4); s += __shfl_xor(s, 8);
    lsum[r] = 1.0f / s;
  }
  if (q0 < LTOT) {
    float* orow = out + ((size_t)b * LTOT + q0) * DIMF + h * HD;
#pragma unroll
    for (int r = 0; r < 4; r++) {
#pragma unroll
      for (int dn = 0; dn < 4; dn++) {
        float* p = orow + (size_t)(lg * 4 + r) * DIMF + dn * 16 + lm;
        *p = *p + acc[dn][r] * lsum[r];
      }
    }
  }
}

extern "C" void kernel_launch(void* const* d_in, const int* in_sizes, int n_in,
                              void* d_out, int out_size, void* d_ws, size_t ws_size,
                              hipStream_t stream) {
  const float* x  = (const float*)d_in[0];
  const float* pv = (const float*)d_in[1];
  float* out = (float*)d_out;
  unsigned short* xnh = (unsigned short*)d_ws;                 // [BH][LP][64] f16
  unsigned short* xnt = xnh + (size_t)BHN * LP * HD;           // [BH][64][LP] f16
  prep_kernel<<<NB * LP, 256, 0, stream>>>(x, pv, out, xnh);
  transpose_kernel<<<BHN * NQT, 256, 0, stream>>>(xnh, xnt);
  attn_kernel<<<BHN * NQT, 256, 0, stream>>>(xnh, xnt, out);
}

// Round 4
// 162.809 us; speedup vs baseline: 3.3071x; 1.0378x over previous
//
#include <hip/hip_runtime.h>
#include <hip/hip_fp16.h>

#define DIMF 1024
#define NHEADS 16
#define SEQ 2048
#define NPV 32
#define HD 64
#define LTOT 2080   // SEQ + NPV
#define LP 2112     // padded: 33*64 = 22*96
#define NB 4
#define BHN 64      // NB * NHEADS
#define NQT 33      // LP/64 (transpose tiles)
#define QB 96       // q rows per block (3 waves x 32)
#define NQB 22      // LP/QB
#define NKV 33      // kv tiles of 64

typedef _Float16 f16x8 __attribute__((ext_vector_type(8)));
typedef float f32x4 __attribute__((ext_vector_type(4)));
typedef float f32x16 __attribute__((ext_vector_type(16)));
typedef unsigned short u16x8 __attribute__((ext_vector_type(8)));
typedef int v2i __attribute__((ext_vector_type(2)));

#if __has_builtin(__builtin_amdgcn_exp2f)
#define EXP2(x) __builtin_amdgcn_exp2f(x)
#else
#define EXP2(x) exp2f(x)
#endif

#define CEXP 0.1803368801111f   // 0.125 * log2(e)
#define KSH  11.5415603271f     // 8 * log2(e)

// ---------------- Kernel 1: paramvec add + LayerNorm + residual ----------------
__global__ __launch_bounds__(256) void prep_kernel(const float* __restrict__ x,
                                                   const float* __restrict__ pv,
                                                   float* __restrict__ out,
                                                   unsigned short* __restrict__ xnh) {
  int row = blockIdx.x;
  int b = row / LP, l = row - b * LP;
  int t = threadIdx.x;
  int h = t >> 4;
  int dd = (t & 15) << 2;
  unsigned short* dst = xnh + ((size_t)(b * NHEADS + h) * LP + l) * HD + dd;
  if (l >= LTOT) {              // zero pad rows (block-uniform -> safe return)
    *reinterpret_cast<ushort4*>(dst) = make_ushort4(0, 0, 0, 0);
    return;
  }
  const float* xr = x + ((size_t)b * LTOT + l) * DIMF + t * 4;
  float4 v = *reinterpret_cast<const float4*>(xr);
  if (l >= SEQ) {
    float4 p = *reinterpret_cast<const float4*>(pv + (size_t)(l - SEQ) * DIMF + t * 4);
    v.x += p.x; v.y += p.y; v.z += p.z; v.w += p.w;
  }
  *reinterpret_cast<float4*>(out + ((size_t)b * LTOT + l) * DIMF + t * 4) = v;

  float s1 = v.x + v.y + v.z + v.w;
  float s2 = v.x * v.x + v.y * v.y + v.z * v.z + v.w * v.w;
#pragma unroll
  for (int o = 1; o < 64; o <<= 1) { s1 += __shfl_xor(s1, o); s2 += __shfl_xor(s2, o); }
  __shared__ float red[8];
  int wv = t >> 6;
  if ((t & 63) == 0) { red[wv] = s1; red[4 + wv] = s2; }
  __syncthreads();
  s1 = red[0] + red[1] + red[2] + red[3];
  s2 = red[4] + red[5] + red[6] + red[7];
  float mu = s1 * (1.0f / DIMF);
  float var = s2 * (1.0f / DIMF) - mu * mu;
  float rs = rsqrtf(var + 1e-5f);
  ushort4 o4;
  o4.x = __half_as_ushort(__float2half((v.x - mu) * rs));
  o4.y = __half_as_ushort(__float2half((v.y - mu) * rs));
  o4.z = __half_as_ushort(__float2half((v.z - mu) * rs));
  o4.w = __half_as_ushort(__float2half((v.w - mu) * rs));
  *reinterpret_cast<ushort4*>(dst) = o4;
}

// ---------------- Kernel 2: per-head transpose [BH][LP][64] -> [BH][64][LP] ----------------
__global__ __launch_bounds__(256) void transpose_kernel(const unsigned short* __restrict__ xnh,
                                                        unsigned short* __restrict__ xnt) {
  __shared__ unsigned short tile[64][72];
  int blk = blockIdx.x;
  int bh = blk / NQT, lt = blk - bh * NQT;
  int t = threadIdx.x;
  int rr = t >> 3;
  int c8 = (t & 7) << 3;
#pragma unroll
  for (int p = 0; p < 2; p++) {
    int ll = rr + p * 32;
    float4 v = *reinterpret_cast<const float4*>(xnh + ((size_t)bh * LP + lt * 64 + ll) * HD + c8);
    int cs = c8 ^ (((ll >> 3) & 7) << 3);
    *reinterpret_cast<float4*>(&tile[ll][cs]) = v;
  }
  __syncthreads();
  int l8 = (t & 7) << 3;
#pragma unroll
  for (int p = 0; p < 2; p++) {
    int d = rr + p * 32;
    u16x8 o;
#pragma unroll
    for (int j = 0; j < 8; j++) {
      o[j] = tile[l8 + j][d ^ ((t & 7) << 3)];
    }
    *reinterpret_cast<u16x8*>(xnt + ((size_t)bh * HD + d) * LP + lt * 64 + l8) = o;
  }
}

// ---------------- Kernel 3: flash attention, swapped QK^T, in-register softmax ----------------
static __device__ __forceinline__ f32x16 mfma32(f16x8 a, f16x8 b, f32x16 c) {
  return __builtin_amdgcn_mfma_f32_32x32x16_f16(a, b, c, 0, 0, 0);
}

static __device__ __forceinline__ unsigned cvtpk(float a, float b) {
  auto h = __builtin_amdgcn_cvt_pkrtz(a, b);   // __fp16 ext_vector(2)
  return __builtin_bit_cast(unsigned, h);
}

// P (f32x16, D-layout of one 32-kv subtile) -> two PV A-frags (kv slices of 16).
// D rows kk(r,hi) = (r&3) + 4*hi + 8*(r>>2). A-frag wants k = hi*8 + i.
// swap(pk(p0,p1), pk(p4,p5)) -> (word0, word2); swap(pk(p2,p3), pk(p6,p7)) -> (word1, word3).
static __device__ __forceinline__ void pack2(const f32x16& P, f16x8& f0, f16x8& f1) {
  unsigned a0 = cvtpk(P[0], P[1]),  b0 = cvtpk(P[4], P[5]);
  unsigned a1 = cvtpk(P[2], P[3]),  b1 = cvtpk(P[6], P[7]);
  v2i s0 = __builtin_amdgcn_permlane32_swap(a0, b0, false, false);
  v2i s1 = __builtin_amdgcn_permlane32_swap(a1, b1, false, false);
  unsigned a2 = cvtpk(P[8], P[9]),   b2 = cvtpk(P[12], P[13]);
  unsigned a3 = cvtpk(P[10], P[11]), b3 = cvtpk(P[14], P[15]);
  v2i s2 = __builtin_amdgcn_permlane32_swap(a2, b2, false, false);
  v2i s3 = __builtin_amdgcn_permlane32_swap(a3, b3, false, false);
  union { unsigned u[4]; f16x8 v; } u0, u1;
  u0.u[0] = (unsigned)s0.x; u0.u[1] = (unsigned)s1.x; u0.u[2] = (unsigned)s0.y; u0.u[3] = (unsigned)s1.y;
  u1.u[0] = (unsigned)s2.x; u1.u[1] = (unsigned)s3.x; u1.u[2] = (unsigned)s2.y; u1.u[3] = (unsigned)s3.y;
  f0 = u0.v; f1 = u1.v;
}

// Stage a 64x64 f16 tile into LDS, 192 threads. Linear LDS dest, inverse-XOR-swizzled
// global source so the swizzled read (chunk c at row r reads c^(r&7)) is conflict-free.
static __device__ __forceinline__ void stage3(const unsigned short* __restrict__ g,
                                              int stride, unsigned short* lds, int tid) {
#pragma unroll
  for (int w = 0; w < 3; w++) {
    int chunk = w * 192 + tid;                  // 16B-chunk id, 512 total
    if (chunk < 512) {                          // wave-uniform (tid<128 for w==2)
      int row = chunk >> 3;
      int gcol = ((chunk & 7) ^ (row & 7)) << 3;
      const unsigned short* src = g + (size_t)row * stride + gcol;
      unsigned short* dst = lds + (size_t)(w * 192 + (tid & ~63)) * 8;  // uniform wave base
      __builtin_amdgcn_global_load_lds(
          (const __attribute__((address_space(1))) unsigned int*)src,
          (__attribute__((address_space(3))) unsigned int*)dst, 16, 0, 0);
    }
  }
}

__device__ __forceinline__ void kv_step32(const unsigned short* kt, const unsigned short* vt,
                                          const f16x8 (&qf)[4], f32x16& accA, f32x16& accB,
                                          float& rowsum, int l31, int hi, int sw) {
  const unsigned short* k0 = kt + (size_t)l31 * 64;   // kv subtile 0, row l31
  const unsigned short* k1 = k0 + 32 * 64;            // kv subtile 1
  f32x16 st0 = {}; f32x16 st1 = {};
  __builtin_amdgcn_s_setprio(1);
#pragma unroll
  for (int ds = 0; ds < 4; ds++) {
    int c = ds * 2 + hi;
    f16x8 ka = *reinterpret_cast<const f16x8*>(k0 + ((c ^ sw) << 3));
    st0 = mfma32(ka, qf[ds], st0);
    f16x8 kb = *reinterpret_cast<const f16x8*>(k1 + ((c ^ sw) << 3));
    st1 = mfma32(kb, qf[ds], st1);
  }
  __builtin_amdgcn_s_setprio(0);
#pragma unroll
  for (int r = 0; r < 16; r++) {
    st0[r] = EXP2(st0[r] * CEXP - KSH); rowsum += st0[r];
    st1[r] = EXP2(st1[r] * CEXP - KSH); rowsum += st1[r];
  }
  f16x8 pa[4];
  pack2(st0, pa[0], pa[1]);   // kv slices 0..15, 16..31
  pack2(st1, pa[2], pa[3]);   // kv slices 32..47, 48..63
  const unsigned short* v0 = vt + (size_t)l31 * 64;   // d subtile 0 (rows d=l31)
  const unsigned short* v1 = v0 + 32 * 64;            // d subtile 1
  __builtin_amdgcn_s_setprio(1);
#pragma unroll
  for (int ks = 0; ks < 4; ks++) {
    int c = ks * 2 + hi;
    f16x8 bv0 = *reinterpret_cast<const f16x8*>(v0 + ((c ^ sw) << 3));
    accA = mfma32(pa[ks], bv0, accA);
    f16x8 bv1 = *reinterpret_cast<const f16x8*>(v1 + ((c ^ sw) << 3));
    accB = mfma32(pa[ks], bv1, accB);
  }
  __builtin_amdgcn_s_setprio(0);
}

__global__ __launch_bounds__(192) void attn_kernel(const unsigned short* __restrict__ xnh,
                                                   const unsigned short* __restrict__ xnt,
                                                   float* __restrict__ out) {
  __shared__ unsigned short ktile[2][64 * 64];
  __shared__ unsigned short vtile[2][64 * 64];
  __shared__ float wred[3][32];
  int bid = blockIdx.x;
  const int nwg = BHN * NQB;        // 1408, %8==0 -> bijective XCD swizzle
  const int cpx = nwg >> 3;
  int wg = (bid & 7) * cpx + (bid >> 3);
  int bh = wg / NQB, qt = wg - bh * NQB;
  int b = bh >> 4, h = bh & 15;
  int tid = threadIdx.x;
  int wid = tid >> 6;
  int lane = tid & 63;
  int l31 = lane & 31, hi = lane >> 5;
  int sw = l31 & 7;
  int qb0 = qt * QB;
  int q0w = qb0 + wid * 32;
  const unsigned short* Kb = xnh + (size_t)bh * (LP * HD);
  const unsigned short* Vb = xnt + (size_t)bh * (HD * LP);

  // Q B-frags hoisted: B[k=d][n=q]: lane q=l31, d = ds*16 + hi*8 + i
  f16x8 qf[4];
#pragma unroll
  for (int ds = 0; ds < 4; ds++)
    qf[ds] = *reinterpret_cast<const f16x8*>(Kb + (size_t)(q0w + l31) * HD + ds * 16 + hi * 8);

  f32x16 accA = {};   // O[q][d 0..31]
  f32x16 accB = {};   // O[q][d 32..63]
  float rowsum = 0.f;

  stage3(Kb, HD, &ktile[0][0], tid);
  stage3(Vb, LP, &vtile[0][0], tid);
  __syncthreads();

  int cur = 0;
  for (int t = 0; t < NKV - 1; ++t) {
    int kv0n = (t + 1) * 64;
    stage3(Kb + (size_t)kv0n * HD, HD, &ktile[cur ^ 1][0], tid);
    stage3(Vb + kv0n, LP, &vtile[cur ^ 1][0], tid);
    kv_step32(&ktile[cur][0], &vtile[cur][0], qf, accA, accB, rowsum, l31, hi, sw);
    __syncthreads();
    cur ^= 1;
  }
  kv_step32(&ktile[cur][0], &vtile[cur][0], qf, accA, accB, rowsum, l31, hi, sw);

  // full row sum (self + hi-partner) minus exact pad contribution (32 zero K-rows)
  float full = rowsum + __shfl_xor(rowsum, 32);
  full -= 32.0f * exp2f(-KSH);
  float inv = 1.0f / full;
  if (lane < 32) wred[wid][l31] = inv;    // same-wave LDS table; compiler orders lgkm
  // epilogue: lane holds O[q=(r&3)+8*(r>>2)+4*hi][d=l31 (+32)]
  float* obase = out + (size_t)b * LTOT * DIMF + h * HD + l31;
#pragma unroll
  for (int q2 = 0; q2 < 4; q2++) {
    float4 iv = *reinterpret_cast<const float4*>(&wred[wid][q2 * 8 + hi * 4]);
#pragma unroll
    for (int j = 0; j < 4; j++) {
      int qg = q0w + q2 * 8 + hi * 4 + j;
      if (qg < LTOT) {
        float* p = obase + (size_t)qg * DIMF;
        float ivj = (j == 0) ? iv.x : (j == 1) ? iv.y : (j == 2) ? iv.z : iv.w;
        p[0]  += accA[q2 * 4 + j] * ivj;
        p[32] += accB[q2 * 4 + j] * ivj;
      }
    }
  }
}

extern "C" void kernel_launch(void* const* d_in, const int* in_sizes, int n_in,
                              void* d_out, int out_size, void* d_ws, size_t ws_size,
                              hipStream_t stream) {
  const float* x  = (const float*)d_in[0];
  const float* pv = (const float*)d_in[1];
  float* out = (float*)d_out;
  unsigned short* xnh = (unsigned short*)d_ws;                 // [BH][LP][64] f16
  unsigned short* xnt = xnh + (size_t)BHN * LP * HD;           // [BH][64][LP] f16
  prep_kernel<<<NB * LP, 256, 0, stream>>>(x, pv, out, xnh);
  transpose_kernel<<<BHN * NQT, 256, 0, stream>>>(xnh, xnt);
  attn_kernel<<<BHN * NQB, 192, 0, stream>>>(xnh, xnt, out);
}

// Round 5
// 126.901 us; speedup vs baseline: 4.2429x; 1.2830x over previous
//
#include <hip/hip_runtime.h>
#include <hip/hip_fp16.h>

#define DIMF 1024
#define NHEADS 16
#define SEQ 2048
#define NPV 32
#define HD 64
#define LTOT 2080   // SEQ + NPV
#define LP 2112     // padded: 33*64
#define NB 4
#define BHN 64      // NB * NHEADS
#define NQT 33      // LP/64 (transpose tiles)
#define QB 128      // q rows per block (4 waves x 32)
#define NQB 17      // ceil(LP/QB); last tile partially wasted
#define NKV 33      // kv tiles of 64

typedef _Float16 f16x8 __attribute__((ext_vector_type(8)));
typedef float f32x16 __attribute__((ext_vector_type(16)));
typedef unsigned short u16x8 __attribute__((ext_vector_type(8)));
typedef int v2i __attribute__((ext_vector_type(2)));

#if __has_builtin(__builtin_amdgcn_exp2f)
#define EXP2(x) __builtin_amdgcn_exp2f(x)
#else
#define EXP2(x) exp2f(x)
#endif

#define CEXP 0.1803368801111f   // 0.125 * log2(e)
#define KSH  11.5415603271f     // 8 * log2(e)

// ---------------- Kernel 1: paramvec add + LayerNorm + residual ----------------
__global__ __launch_bounds__(256) void prep_kernel(const float* __restrict__ x,
                                                   const float* __restrict__ pv,
                                                   float* __restrict__ out,
                                                   unsigned short* __restrict__ xnh) {
  int row = blockIdx.x;
  int b = row / LP, l = row - b * LP;
  int t = threadIdx.x;
  int h = t >> 4;
  int dd = (t & 15) << 2;
  unsigned short* dst = xnh + ((size_t)(b * NHEADS + h) * LP + l) * HD + dd;
  if (l >= LTOT) {              // zero pad rows (block-uniform -> safe return)
    *reinterpret_cast<ushort4*>(dst) = make_ushort4(0, 0, 0, 0);
    return;
  }
  const float* xr = x + ((size_t)b * LTOT + l) * DIMF + t * 4;
  float4 v = *reinterpret_cast<const float4*>(xr);
  if (l >= SEQ) {
    float4 p = *reinterpret_cast<const float4*>(pv + (size_t)(l - SEQ) * DIMF + t * 4);
    v.x += p.x; v.y += p.y; v.z += p.z; v.w += p.w;
  }
  *reinterpret_cast<float4*>(out + ((size_t)b * LTOT + l) * DIMF + t * 4) = v;

  float s1 = v.x + v.y + v.z + v.w;
  float s2 = v.x * v.x + v.y * v.y + v.z * v.z + v.w * v.w;
#pragma unroll
  for (int o = 1; o < 64; o <<= 1) { s1 += __shfl_xor(s1, o); s2 += __shfl_xor(s2, o); }
  __shared__ float red[8];
  int wv = t >> 6;
  if ((t & 63) == 0) { red[wv] = s1; red[4 + wv] = s2; }
  __syncthreads();
  s1 = red[0] + red[1] + red[2] + red[3];
  s2 = red[4] + red[5] + red[6] + red[7];
  float mu = s1 * (1.0f / DIMF);
  float var = s2 * (1.0f / DIMF) - mu * mu;
  float rs = rsqrtf(var + 1e-5f);
  ushort4 o4;
  o4.x = __half_as_ushort(__float2half((v.x - mu) * rs));
  o4.y = __half_as_ushort(__float2half((v.y - mu) * rs));
  o4.z = __half_as_ushort(__float2half((v.z - mu) * rs));
  o4.w = __half_as_ushort(__float2half((v.w - mu) * rs));
  *reinterpret_cast<ushort4*>(dst) = o4;
}

// ---------------- Kernel 2: per-head transpose [BH][LP][64] -> [BH][64][LP] ----------------
__global__ __launch_bounds__(256) void transpose_kernel(const unsigned short* __restrict__ xnh,
                                                        unsigned short* __restrict__ xnt) {
  __shared__ unsigned short tile[64][72];
  int blk = blockIdx.x;
  int bh = blk / NQT, lt = blk - bh * NQT;
  int t = threadIdx.x;
  int rr = t >> 3;
  int c8 = (t & 7) << 3;
#pragma unroll
  for (int p = 0; p < 2; p++) {
    int ll = rr + p * 32;
    float4 v = *reinterpret_cast<const float4*>(xnh + ((size_t)bh * LP + lt * 64 + ll) * HD + c8);
    int cs = c8 ^ (((ll >> 3) & 7) << 3);
    *reinterpret_cast<float4*>(&tile[ll][cs]) = v;
  }
  __syncthreads();
  int l8 = (t & 7) << 3;
#pragma unroll
  for (int p = 0; p < 2; p++) {
    int d = rr + p * 32;
    u16x8 o;
#pragma unroll
    for (int j = 0; j < 8; j++) {
      o[j] = tile[l8 + j][d ^ ((t & 7) << 3)];
    }
    *reinterpret_cast<u16x8*>(xnt + ((size_t)bh * HD + d) * LP + lt * 64 + l8) = o;
  }
}

// ---------------- Kernel 3: flash attention, swapped QK^T, in-register softmax ----------------
static __device__ __forceinline__ f32x16 mfma32(f16x8 a, f16x8 b, f32x16 c) {
  return __builtin_amdgcn_mfma_f32_32x32x16_f16(a, b, c, 0, 0, 0);
}

static __device__ __forceinline__ unsigned cvtpk(float a, float b) {
  auto h = __builtin_amdgcn_cvt_pkrtz(a, b);
  return __builtin_bit_cast(unsigned, h);
}

static __device__ __forceinline__ void pack2(const f32x16& P, f16x8& f0, f16x8& f1) {
  unsigned a0 = cvtpk(P[0], P[1]),  b0 = cvtpk(P[4], P[5]);
  unsigned a1 = cvtpk(P[2], P[3]),  b1 = cvtpk(P[6], P[7]);
  v2i s0 = __builtin_amdgcn_permlane32_swap(a0, b0, false, false);
  v2i s1 = __builtin_amdgcn_permlane32_swap(a1, b1, false, false);
  unsigned a2 = cvtpk(P[8], P[9]),   b2 = cvtpk(P[12], P[13]);
  unsigned a3 = cvtpk(P[10], P[11]), b3 = cvtpk(P[14], P[15]);
  v2i s2 = __builtin_amdgcn_permlane32_swap(a2, b2, false, false);
  v2i s3 = __builtin_amdgcn_permlane32_swap(a3, b3, false, false);
  union { unsigned u[4]; f16x8 v; } u0, u1;
  u0.u[0] = (unsigned)s0.x; u0.u[1] = (unsigned)s1.x; u0.u[2] = (unsigned)s0.y; u0.u[3] = (unsigned)s1.y;
  u1.u[0] = (unsigned)s2.x; u1.u[1] = (unsigned)s3.x; u1.u[2] = (unsigned)s2.y; u1.u[3] = (unsigned)s3.y;
  f0 = u0.v; f1 = u1.v;
}

#define GLDS(src, dst) \
  __builtin_amdgcn_global_load_lds( \
      (const __attribute__((address_space(1))) unsigned int*)(src), \
      (__attribute__((address_space(3))) unsigned int*)(dst), 16, 0, 0)

__device__ __forceinline__ void kv_step32(const unsigned short* kbuf, const unsigned short* vbuf,
                                          const f16x8 (&qf)[4], f32x16& accA, f32x16& accB,
                                          float& rowsum, int l31, int hi, int sw) {
  const unsigned short* k0 = kbuf + (size_t)l31 * 64;
  const unsigned short* k1 = k0 + 32 * 64;
  f32x16 st0 = {}; f32x16 st1 = {};
  __builtin_amdgcn_s_setprio(1);
#pragma unroll
  for (int ds = 0; ds < 4; ds++) {
    int c = ds * 2 + hi;
    f16x8 ka = *reinterpret_cast<const f16x8*>(k0 + ((c ^ sw) << 3));
    st0 = mfma32(ka, qf[ds], st0);
    f16x8 kb = *reinterpret_cast<const f16x8*>(k1 + ((c ^ sw) << 3));
    st1 = mfma32(kb, qf[ds], st1);
  }
  __builtin_amdgcn_s_setprio(0);
#pragma unroll
  for (int r = 0; r < 16; r++) {
    st0[r] = EXP2(st0[r] * CEXP - KSH); rowsum += st0[r];
    st1[r] = EXP2(st1[r] * CEXP - KSH); rowsum += st1[r];
  }
  f16x8 pa[4];
  pack2(st0, pa[0], pa[1]);
  pack2(st1, pa[2], pa[3]);
  const unsigned short* v0 = vbuf + (size_t)l31 * 64;
  const unsigned short* v1 = v0 + 32 * 64;
  __builtin_amdgcn_s_setprio(1);
#pragma unroll
  for (int ks = 0; ks < 4; ks++) {
    int c = ks * 2 + hi;
    f16x8 bv0 = *reinterpret_cast<const f16x8*>(v0 + ((c ^ sw) << 3));
    accA = mfma32(pa[ks], bv0, accA);
    f16x8 bv1 = *reinterpret_cast<const f16x8*>(v1 + ((c ^ sw) << 3));
    accB = mfma32(pa[ks], bv1, accB);
  }
  __builtin_amdgcn_s_setprio(0);
}

__global__ __launch_bounds__(256, 4) void attn_kernel(const unsigned short* __restrict__ xnh,
                                                      const unsigned short* __restrict__ xnt,
                                                      float* __restrict__ out) {
  __shared__ unsigned short kt0[64 * 64], kt1[64 * 64];
  __shared__ unsigned short vt0[64 * 64], vt1[64 * 64];
  __shared__ float wred[4][32];
  int bid = blockIdx.x;
  const int nwg = BHN * NQB;        // 1088, %8==0 -> bijective XCD swizzle
  const int cpx = nwg >> 3;
  int wg = (bid & 7) * cpx + (bid >> 3);
  int bh = wg / NQB, qt = wg - bh * NQB;
  int b = bh >> 4, h = bh & 15;
  int tid = threadIdx.x;
  int wid = tid >> 6;
  int lane = tid & 63;
  int l31 = lane & 31, hi = lane >> 5;
  int sw = l31 & 7;
  int q0w = qt * QB + wid * 32;     // may exceed LTOT for last q-tile (discarded, guarded)
  const unsigned short* Kb = xnh + (size_t)bh * (LP * HD);
  const unsigned short* Vb = xnt + (size_t)bh * (HD * LP);

  f16x8 qf[4];
#pragma unroll
  for (int ds = 0; ds < 4; ds++)
    qf[ds] = *reinterpret_cast<const f16x8*>(Kb + (size_t)(q0w + l31) * HD + ds * 16 + hi * 8);

  f32x16 accA = {};
  f32x16 accB = {};
  float rowsum = 0.f;

  // Affine per-thread stage sources: chunk0 = tid (rows 0..31), chunk1 = tid+256 (rows 32..63)
  int srow = tid >> 3;
  int scol = ((tid & 7) ^ (srow & 7)) << 3;
  const unsigned short* pK = Kb + (size_t)srow * HD + scol;
  const unsigned short* pV = Vb + (size_t)srow * LP + scol;
  unsigned short* dK0lo = kt0 + (size_t)(wid * 64) * 8;
  unsigned short* dK0hi = kt0 + (size_t)(256 + wid * 64) * 8;
  unsigned short* dK1lo = kt1 + (size_t)(wid * 64) * 8;
  unsigned short* dK1hi = kt1 + (size_t)(256 + wid * 64) * 8;
  unsigned short* dV0lo = vt0 + (size_t)(wid * 64) * 8;
  unsigned short* dV0hi = vt0 + (size_t)(256 + wid * 64) * 8;
  unsigned short* dV1lo = vt1 + (size_t)(wid * 64) * 8;
  unsigned short* dV1hi = vt1 + (size_t)(256 + wid * 64) * 8;

#define STAGE0() do { GLDS(pK, dK0lo); GLDS(pK + 32 * HD, dK0hi); \
                      GLDS(pV, dV0lo); GLDS(pV + 32 * LP, dV0hi); \
                      pK += 64 * HD; pV += 64; } while (0)
#define STAGE1() do { GLDS(pK, dK1lo); GLDS(pK + 32 * HD, dK1hi); \
                      GLDS(pV, dV1lo); GLDS(pV + 32 * LP, dV1hi); \
                      pK += 64 * HD; pV += 64; } while (0)

  STAGE0();               // tile 0
  __syncthreads();

  for (int it = 0; it < 16; ++it) {
    STAGE1();             // stage tile 2it+1
    kv_step32(kt0, vt0, qf, accA, accB, rowsum, l31, hi, sw);   // compute tile 2it
    __syncthreads();
    STAGE0();             // stage tile 2it+2
    kv_step32(kt1, vt1, qf, accA, accB, rowsum, l31, hi, sw);   // compute tile 2it+1
    __syncthreads();
  }
  kv_step32(kt0, vt0, qf, accA, accB, rowsum, l31, hi, sw);     // compute tile 32

  float full = rowsum + __shfl_xor(rowsum, 32);
  full -= 32.0f * exp2f(-KSH);    // exact pad contribution (32 zero K-rows)
  float inv = 1.0f / full;
  if (lane < 32) wred[wid][l31] = inv;
  float* obase = out + (size_t)b * LTOT * DIMF + h * HD + l31;
  if (q0w < LTOT) {               // wave-uniform guard
#pragma unroll
    for (int q2 = 0; q2 < 4; q2++) {
      float4 iv = *reinterpret_cast<const float4*>(&wred[wid][q2 * 8 + hi * 4]);
#pragma unroll
      for (int j = 0; j < 4; j++) {
        int qg = q0w + q2 * 8 + hi * 4 + j;
        float* p = obase + (size_t)qg * DIMF;
        float ivj = (j == 0) ? iv.x : (j == 1) ? iv.y : (j == 2) ? iv.z : iv.w;
        p[0]  += accA[q2 * 4 + j] * ivj;
        p[32] += accB[q2 * 4 + j] * ivj;
      }
    }
  }
#undef STAGE0
#undef STAGE1
}

extern "C" void kernel_launch(void* const* d_in, const int* in_sizes, int n_in,
                              void* d_out, int out_size, void* d_ws, size_t ws_size,
                              hipStream_t stream) {
  const float* x  = (const float*)d_in[0];
  const float* pv = (const float*)d_in[1];
  float* out = (float*)d_out;
  unsigned short* xnh = (unsigned short*)d_ws;                 // [BH][LP][64] f16
  unsigned short* xnt = xnh + (size_t)BHN * LP * HD;           // [BH][64][LP] f16
  prep_kernel<<<NB * LP, 256, 0, stream>>>(x, pv, out, xnh);
  transpose_kernel<<<BHN * NQT, 256, 0, stream>>>(xnh, xnt);
  attn_kernel<<<BHN * NQB, 256, 0, stream>>>(xnh, xnt, out);
}